// Round 1
// baseline (796.539 us; speedup 1.0000x reference)
//
#include <hip/hip_runtime.h>

// ---------------------------------------------------------------------------
// Tree-MLP fused kernel, fp32 baseline (round 1).
//
// Algebra: emb is folded into the tree weights:
//   Wt0[k][h] (35x64)  = [ W0[:, :64] @ W_emb ; W0[:, 64:67] ]^T   (leaf)
//   Wt1[k][h] (163x64) = [ W1[:, :64] @ W_emb ; W1[:, 64:67] ;
//                          W1[:, 67:131] ; W1[:, 131:195] ]^T      (internal)
//   b0p = b0 + W0[:, :64] @ b_emb ; b1p = b1 + W1[:, :64] @ b_emb
// so each node input is [x0_row(35), h_left(64), h_right(64)].
//
// tree_kernel: 1 block per p. lane=node, waves split the 64 outputs
// (CH accumulators per lane, fully unrolled). W operand is wave-uniform
// (readfirstlane'd wave id) -> s_load. h in LDS with XOR swizzle
// (h ^ ((node>>1)&31)) so child reads / writes are <=2-way (free).
// ---------------------------------------------------------------------------

#define NNODE 511
#define KX    35      // T + EXTRA
#define KTOT  163     // 35 + 64 + 64

// ws float layout
#define WS_WT0   0        // 35*64 = 2240
#define WS_B0P   2240     // 64
#define WS_WT1   2304     // 163*64 = 10432
#define WS_B1P   12736    // 64
#define WS_H0    12800    // 2560*64 = 163840
#define WS_MH    176640   // 512*64 = 32768

__global__ void prep_kernel(const float* __restrict__ W_emb, const float* __restrict__ b_emb,
                            const float* __restrict__ W0, const float* __restrict__ b0,
                            const float* __restrict__ W1, const float* __restrict__ b1,
                            float* __restrict__ ws)
{
    int idx = blockIdx.x * blockDim.x + threadIdx.x;
    float* Wt0 = ws + WS_WT0;
    float* b0p = ws + WS_B0P;
    float* Wt1 = ws + WS_WT1;
    float* b1p = ws + WS_B1P;
    if (idx < 2240) {
        int k = idx >> 6, h = idx & 63;
        float v;
        if (k < 32) { v = 0.f; for (int e = 0; e < 64; e++) v = fmaf(W0[h*67+e], W_emb[e*32+k], v); }
        else        v = W0[h*67 + 64 + (k-32)];
        Wt0[k*64+h] = v;
    } else if (idx < 2304) {
        int h = idx - 2240;
        float v = b0[h];
        for (int e = 0; e < 64; e++) v = fmaf(W0[h*67+e], b_emb[e], v);
        b0p[h] = v;
    } else if (idx < 12736) {
        int j = idx - 2304; int k = j >> 6, h = j & 63;
        float v;
        if (k < 32)      { v = 0.f; for (int e = 0; e < 64; e++) v = fmaf(W1[h*195+e], W_emb[e*32+k], v); }
        else if (k < 35)   v = W1[h*195 + 64  + (k-32)];
        else if (k < 99)   v = W1[h*195 + 67  + (k-35)];
        else               v = W1[h*195 + 131 + (k-99)];
        Wt1[k*64+h] = v;
    } else if (idx < 12800) {
        int h = idx - 12736;
        float v = b1[h];
        for (int e = 0; e < 64; e++) v = fmaf(W1[h*195+e], b_emb[e], v);
        b1p[h] = v;
    }
}

// Internal tree level. GN node-groups of 64 (GN = n/64 for n>=64 else 1),
// 8/GN h-chunks of CH = 64*GN/8 outputs each. NLEV = node count this level.
template<int GN, int CH, int NLEV>
__device__ __forceinline__ void tree_level(int lane, int wv, int p,
                                           const float* __restrict__ x0,
                                           const float* __restrict__ Wt1,
                                           const float* __restrict__ b1p,
                                           const float* bufR, float* bufW, int nb)
{
    constexpr int HW = 8 / GN;
    int g  = wv / HW;
    int hq = wv % HW;
    int nl = g * 64 + lane;
    bool active = (GN > 1) || (lane < NLEV);
    if (active) {
        float acc[CH];
        const float* bb = b1p + hq * CH;
        #pragma unroll
        for (int i = 0; i < CH; i++) acc[i] = bb[i];

        // x0 part, k = 0..34 (per-lane global read; L1 absorbs the stride)
        const float* xr = x0 + ((size_t)p * NNODE + nb + nl) * KX;
        #pragma unroll 5
        for (int k = 0; k < KX; k++) {
            float v = xr[k];
            const float* w = Wt1 + k * 64 + hq * CH;
            #pragma unroll
            for (int i = 0; i < CH; i++) acc[i] = fmaf(w[i], v, acc[i]);
        }
        // left child, k = 35..98
        int sw = nl & 31;   // == ((2nl)>>1)&31 == ((2nl+1)>>1)&31
        const float* cl = bufR + (2 * nl) * 64;
        #pragma unroll 4
        for (int k = 0; k < 64; k++) {
            float v = cl[k ^ sw];
            const float* w = Wt1 + (KX + k) * 64 + hq * CH;
            #pragma unroll
            for (int i = 0; i < CH; i++) acc[i] = fmaf(w[i], v, acc[i]);
        }
        // right child, k = 99..162
        const float* cr = bufR + (2 * nl + 1) * 64;
        #pragma unroll 4
        for (int k = 0; k < 64; k++) {
            float v = cr[k ^ sw];
            const float* w = Wt1 + (99 + k) * 64 + hq * CH;
            #pragma unroll
            for (int i = 0; i < CH; i++) acc[i] = fmaf(w[i], v, acc[i]);
        }
        // relu + swizzled store
        int so = (nl >> 1) & 31;
        #pragma unroll
        for (int i = 0; i < CH; i++) {
            int h = hq * CH + i;
            bufW[nl * 64 + (h ^ so)] = fmaxf(acc[i], 0.f);
        }
    }
    __syncthreads();
}

__global__ __launch_bounds__(512, 2) void tree_kernel(const float* __restrict__ x0,
                                                      const float* __restrict__ wsw,
                                                      float* __restrict__ h0out)
{
    __shared__ float buf0[256 * 64];   // 64 KB
    __shared__ float buf1[128 * 64];   // 32 KB
    const float* Wt0 = wsw + WS_WT0;
    const float* b0p = wsw + WS_B0P;
    const float* Wt1 = wsw + WS_WT1;
    const float* b1p = wsw + WS_B1P;

    int p    = blockIdx.x;
    int lane = threadIdx.x & 63;
    int wv   = __builtin_amdgcn_readfirstlane((int)(threadIdx.x >> 6));  // 0..7

    // ---- leaf level (256 nodes, K=35, W0): GN=4, 2 h-chunks of 32 ----
    {
        int g = wv >> 1, hq = wv & 1;
        int nl = g * 64 + lane;                 // 0..255
        float acc[32];
        const float* bb = b0p + hq * 32;
        #pragma unroll
        for (int i = 0; i < 32; i++) acc[i] = bb[i];
        const float* xr = x0 + ((size_t)p * NNODE + 255 + nl) * KX;
        #pragma unroll 5
        for (int k = 0; k < KX; k++) {
            float v = xr[k];
            const float* w = Wt0 + k * 64 + hq * 32;
            #pragma unroll
            for (int i = 0; i < 32; i++) acc[i] = fmaf(w[i], v, acc[i]);
        }
        int so = (nl >> 1) & 31;
        #pragma unroll
        for (int i = 0; i < 32; i++) {
            int h = hq * 32 + i;
            buf0[nl * 64 + (h ^ so)] = fmaxf(acc[i], 0.f);
        }
    }
    __syncthreads();

    tree_level<2, 16, 128>(lane, wv, p, x0, Wt1, b1p, buf0, buf1, 127); // l=7
    tree_level<1,  8,  64>(lane, wv, p, x0, Wt1, b1p, buf1, buf0,  63); // l=6
    tree_level<1,  8,  32>(lane, wv, p, x0, Wt1, b1p, buf0, buf1,  31); // l=5
    tree_level<1,  8,  16>(lane, wv, p, x0, Wt1, b1p, buf1, buf0,  15); // l=4
    tree_level<1,  8,   8>(lane, wv, p, x0, Wt1, b1p, buf0, buf1,   7); // l=3
    tree_level<1,  8,   4>(lane, wv, p, x0, Wt1, b1p, buf1, buf0,   3); // l=2
    tree_level<1,  8,   2>(lane, wv, p, x0, Wt1, b1p, buf0, buf1,   1); // l=1
    tree_level<1,  8,   1>(lane, wv, p, x0, Wt1, b1p, buf1, buf0,   0); // l=0

    if (threadIdx.x < 64)   // node 0 swizzle is identity
        h0out[(size_t)p * 64 + threadIdx.x] = buf0[threadIdx.x];
}

__global__ void mean_kernel(const float* __restrict__ h0, float* __restrict__ mh)
{
    int idx = blockIdx.x * blockDim.x + threadIdx.x;   // 512*64
    if (idx < 512 * 64) {
        int g = idx >> 6, h = idx & 63;
        float s = 0.f;
        #pragma unroll
        for (int q = 0; q < 5; q++) s += h0[(size_t)(g * 5 + q) * 64 + h];
        mh[idx] = s * 0.2f;
    }
}

__global__ __launch_bounds__(64) void head_kernel(const float* __restrict__ x,
                                                  const float* __restrict__ mh,
                                                  const float* __restrict__ Wfc1,
                                                  const float* __restrict__ bfc1,
                                                  const float* __restrict__ Wfc2,
                                                  const float* __restrict__ bfc2,
                                                  float* __restrict__ out)
{
    __shared__ float sw[64];
    __shared__ float sh[64];
    int b = blockIdx.x, h = threadIdx.x;

    float a0 = 0.f, a1 = 0.f, a2 = 0.f, a3 = 0.f;
    const float* xr = x + (size_t)b * 512;
    for (int g = 0; g < 512; g += 4) {
        a0 = fmaf(xr[g + 0], mh[(g + 0) * 64 + h], a0);
        a1 = fmaf(xr[g + 1], mh[(g + 1) * 64 + h], a1);
        a2 = fmaf(xr[g + 2], mh[(g + 2) * 64 + h], a2);
        a3 = fmaf(xr[g + 3], mh[(g + 3) * 64 + h], a3);
    }
    sw[h] = (a0 + a1) + (a2 + a3);
    __syncthreads();

    float acc = bfc1[h];
    #pragma unroll 8
    for (int k = 0; k < 64; k++) acc = fmaf(Wfc1[h * 64 + k], sw[k], acc);
    sh[h] = fmaxf(acc, 0.f);
    __syncthreads();

    if (h < 8) {
        float o = bfc2[h];
        #pragma unroll 8
        for (int f = 0; f < 64; f++) o = fmaf(Wfc2[h * 64 + f], sh[f], o);
        out[(size_t)b * 8 + h] = o;
    }
}

extern "C" void kernel_launch(void* const* d_in, const int* in_sizes, int n_in,
                              void* d_out, int out_size, void* d_ws, size_t ws_size,
                              hipStream_t stream)
{
    (void)in_sizes; (void)n_in; (void)out_size; (void)ws_size;
    const float* x     = (const float*)d_in[0];
    const float* x0    = (const float*)d_in[1];
    const float* W_emb = (const float*)d_in[2];
    const float* b_emb = (const float*)d_in[3];
    const float* W0    = (const float*)d_in[4];
    const float* b0    = (const float*)d_in[5];
    const float* W1    = (const float*)d_in[6];
    const float* b1    = (const float*)d_in[7];
    const float* Wfc1  = (const float*)d_in[8];
    const float* bfc1  = (const float*)d_in[9];
    const float* Wfc2  = (const float*)d_in[10];
    const float* bfc2  = (const float*)d_in[11];

    float* ws  = (float*)d_ws;          // needs ~840 KB of ws
    float* h0  = ws + WS_H0;
    float* mh  = ws + WS_MH;
    float* out = (float*)d_out;

    prep_kernel<<<50, 256, 0, stream>>>(W_emb, b_emb, W0, b0, W1, b1, ws);
    tree_kernel<<<2560, 512, 0, stream>>>(x0, ws, h0);
    mean_kernel<<<128, 256, 0, stream>>>(h0, mh);
    head_kernel<<<512, 64, 0, stream>>>(x, mh, Wfc1, bfc1, Wfc2, bfc2, out);
}

// Round 2
// 128.898 us; speedup vs baseline: 6.1796x; 6.1796x over previous
//
#include <hip/hip_runtime.h>
#include <hip/hip_bf16.h>

// ---------------------------------------------------------------------------
// Tree-MLP, MFMA bf16 version (round 2).
// Per level: GEMM rows=(nodes x 2 trees), K=163 (=35 x0 + 64 hL + 64 hR), N=64.
// emb folded into weights (prep). h in LDS bf16, XOR-swizzled. x0 fragment-
// loaded from global with on-the-fly bf16 convert. fp32 accumulation.
// ---------------------------------------------------------------------------

typedef __attribute__((ext_vector_type(8))) short s8v;   // 8 bf16 = 4 VGPR
typedef __attribute__((ext_vector_type(4))) float f4v;   // MFMA C/D

__device__ __forceinline__ unsigned short f2bf(float f) {
    return __builtin_bit_cast(unsigned short, __float2bfloat16(f));
}

__device__ __forceinline__ f4v mfma16(s8v a, s8v b, f4v c) {
    return __builtin_amdgcn_mfma_f32_16x16x32_bf16(a, b, c, 0, 0, 0);
}

// swizzle: 8-granular XOR of h-index with row bits {0,2,3} -> conflict-free-ish
#define SWZ(r) ((((r) & 1) | (((r) >> 1) & 6)) << 3)

// pack 8 consecutive fp32 -> bf16x8 frag
__device__ __forceinline__ s8v pack8(const float* __restrict__ p) {
    s8v r;
    #pragma unroll
    for (int j = 0; j < 8; j++) r[j] = (short)f2bf(p[j]);
    return r;
}
// x0 tail frag (k=32..34 valid only in quarter 0)
__device__ __forceinline__ s8v xtail(const float* __restrict__ xr, int lq) {
    s8v r = {0, 0, 0, 0, 0, 0, 0, 0};
    if (lq == 0) {
        r[0] = (short)f2bf(xr[32]);
        r[1] = (short)f2bf(xr[33]);
        r[2] = (short)f2bf(xr[34]);
    }
    return r;
}

// ws layout (bytes): wt1u[64*192] (24576B) | wt0u[64*64] (8192B) |
//                    b1p f32[64] | b0p f32[64] | h0 f32[2560*64] | mh f32[512*64]

__global__ void prep_kernel(const float* __restrict__ W_emb, const float* __restrict__ b_emb,
                            const float* __restrict__ W0, const float* __restrict__ b0,
                            const float* __restrict__ W1, const float* __restrict__ b1,
                            unsigned short* __restrict__ wt1, unsigned short* __restrict__ wt0,
                            float* __restrict__ b1p, float* __restrict__ b0p)
{
    int idx = blockIdx.x * 256 + threadIdx.x;
    if (idx < 64 * 192) {
        int h = idx / 192, k = idx % 192;
        float v;
        if (k < 32) { v = 0.f; for (int e = 0; e < 64; e++) v = fmaf(W1[h*195+e], W_emb[e*32+k], v); }
        else if (k < 35)  v = W1[h*195 + 64 + (k - 32)];
        else if (k < 64)  v = 0.f;
        else              v = W1[h*195 + 67 + (k - 64)];   // hL (64) then hR (64), contiguous
        wt1[h*192 + k] = f2bf(v);
    } else if (idx < 64*192 + 64*64) {
        int j = idx - 64*192; int h = j >> 6, k = j & 63;
        float v;
        if (k < 32)      { v = 0.f; for (int e = 0; e < 64; e++) v = fmaf(W0[h*67+e], W_emb[e*32+k], v); }
        else if (k < 35)   v = W0[h*67 + 64 + (k - 32)];
        else               v = 0.f;
        wt0[h*64 + k] = f2bf(v);
    } else if (idx < 64*192 + 64*64 + 64) {
        int h = idx - (64*192 + 64*64);
        float v = b1[h];
        for (int e = 0; e < 64; e++) v = fmaf(W1[h*195+e], b_emb[e], v);
        b1p[h] = v;
    } else if (idx < 64*192 + 64*64 + 128) {
        int h = idx - (64*192 + 64*64 + 64);
        float v = b0[h];
        for (int e = 0; e < 64; e++) v = fmaf(W0[h*67+e], b_emb[e], v);
        b0p[h] = v;
    }
}

__global__ __launch_bounds__(512, 2) void tree_kernel(
    const float* __restrict__ x0,
    const unsigned short* __restrict__ wt1,
    const unsigned short* __restrict__ wt0,
    const float* __restrict__ b1p,
    const float* __restrict__ b0p,
    float* __restrict__ h0out)
{
    __shared__ __align__(16) unsigned short buf0[512 * 64];  // 64 KB
    __shared__ __align__(16) unsigned short buf1[256 * 64];  // 32 KB

    const int l  = threadIdx.x & 63;
    const int w  = threadIdx.x >> 6;   // 0..7
    const int c2 = w & 1;              // col-pair (32 cols)
    const int wr = w >> 1;             // row-split 0..3
    const int lq = l >> 4;
    const int lm = l & 15;
    const int p0 = blockIdx.x * 2;

    // --- resident B-frags (weights, bf16) + bias ---
    s8v wH[2][4], wX[2][2], wL[2][2];
    f4v binit1[2], binit0[2];
    #pragma unroll
    for (int cc = 0; cc < 2; cc++) {
        int col = c2*32 + cc*16 + lm;
        #pragma unroll
        for (int ks = 0; ks < 4; ks++)
            wH[cc][ks] = *(const s8v*)(wt1 + col*192 + 64 + ks*32 + lq*8);
        #pragma unroll
        for (int ks = 0; ks < 2; ks++) {
            wX[cc][ks] = *(const s8v*)(wt1 + col*192 + ks*32 + lq*8);
            wL[cc][ks] = *(const s8v*)(wt0 + col*64  + ks*32 + lq*8);
        }
        float bv1 = b1p[col], bv0 = b0p[col];
        binit1[cc] = (f4v){bv1, bv1, bv1, bv1};
        binit0[cc] = (f4v){bv0, bv0, bv0, bv0};
    }

    // --- leaf level: 256 nodes x 2 trees = 512 rows, K=35 (2 K-steps) ---
    for (int rt = wr; rt < 32; rt += 4) {
        const int R0  = rt * 16;
        const int row = R0 + lm;
        const float* xr = x0 + ((size_t)(p0 + (row & 1)) * 511 + 255 + (row >> 1)) * 35;
        s8v a0 = pack8(xr + lq*8);
        s8v a1 = xtail(xr, lq);
        f4v acc0 = binit0[0], acc1 = binit0[1];
        acc0 = mfma16(a0, wL[0][0], acc0);
        acc1 = mfma16(a0, wL[1][0], acc1);
        acc0 = mfma16(a1, wL[0][1], acc0);
        acc1 = mfma16(a1, wL[1][1], acc1);
        #pragma unroll
        for (int r = 0; r < 4; r++) {
            int ro = R0 + lq*4 + r;
            int sw = SWZ(ro);
            buf0[ro*64 + ((c2*32 +      lm) ^ sw)] = f2bf(fmaxf(acc0[r], 0.f));
            buf0[ro*64 + ((c2*32 + 16 + lm) ^ sw)] = f2bf(fmaxf(acc1[r], 0.f));
        }
    }
    __syncthreads();

    // --- internal levels (K = 35 x0 + 128 children) ---
    auto level = [&](int lo, int RT, const unsigned short* bufR, unsigned short* bufW) {
        for (int rt = wr; rt < RT; rt += 4) {
            const int R0  = rt * 16;
            const int row = R0 + lm;
            const int n = row >> 1, t = row & 1;
            const float* xr = x0 + ((size_t)(p0 + t) * 511 + lo + n) * 35;
            s8v a0 = pack8(xr + lq*8);
            s8v a1 = xtail(xr, lq);
            f4v acc0 = binit1[0], acc1 = binit1[1];
            acc0 = mfma16(a0, wX[0][0], acc0);
            acc1 = mfma16(a0, wX[1][0], acc1);
            acc0 = mfma16(a1, wX[0][1], acc0);
            acc1 = mfma16(a1, wX[1][1], acc1);
            #pragma unroll
            for (int ks = 0; ks < 4; ks++) {
                int k0 = ks*32 + lq*8;
                int rr = (2*n + (k0 >> 6)) * 2 + t;
                s8v a = *(const s8v*)(bufR + rr*64 + ((k0 & 63) ^ SWZ(rr)));
                acc0 = mfma16(a, wH[0][ks], acc0);
                acc1 = mfma16(a, wH[1][ks], acc1);
            }
            #pragma unroll
            for (int r = 0; r < 4; r++) {
                int ro = R0 + lq*4 + r;
                int sw = SWZ(ro);
                bufW[ro*64 + ((c2*32 +      lm) ^ sw)] = f2bf(fmaxf(acc0[r], 0.f));
                bufW[ro*64 + ((c2*32 + 16 + lm) ^ sw)] = f2bf(fmaxf(acc1[r], 0.f));
            }
        }
        __syncthreads();
    };

    level(127, 16, buf0, buf1);   // l=7
    level( 63,  8, buf1, buf0);   // l=6
    level( 31,  4, buf0, buf1);   // l=5
    level( 15,  2, buf1, buf0);   // l=4
    level(  7,  1, buf0, buf1);   // l=3
    level(  3,  1, buf1, buf0);   // l=2
    level(  1,  1, buf0, buf1);   // l=1

    // --- level 0: 1 node x 2 trees, write fp32 h0 to global ---
    if (wr == 0) {
        const int row = lm;
        const int n = row >> 1, t = row & 1;
        const float* xr = x0 + ((size_t)(p0 + t) * 511 + n) * 35;
        s8v a0 = pack8(xr + lq*8);
        s8v a1 = xtail(xr, lq);
        f4v acc0 = binit1[0], acc1 = binit1[1];
        acc0 = mfma16(a0, wX[0][0], acc0);
        acc1 = mfma16(a0, wX[1][0], acc1);
        acc0 = mfma16(a1, wX[0][1], acc0);
        acc1 = mfma16(a1, wX[1][1], acc1);
        #pragma unroll
        for (int ks = 0; ks < 4; ks++) {
            int k0 = ks*32 + lq*8;
            int rr = (2*n + (k0 >> 6)) * 2 + t;
            s8v a = *(const s8v*)(buf1 + rr*64 + ((k0 & 63) ^ SWZ(rr)));
            acc0 = mfma16(a, wH[0][ks], acc0);
            acc1 = mfma16(a, wH[1][ks], acc1);
        }
        if (lq == 0) {
            #pragma unroll
            for (int r = 0; r < 2; r++) {   // rows 0,1 = trees p0, p0+1
                h0out[(size_t)(p0 + r) * 64 + c2*32 +      lm] = fmaxf(acc0[r], 0.f);
                h0out[(size_t)(p0 + r) * 64 + c2*32 + 16 + lm] = fmaxf(acc1[r], 0.f);
            }
        }
    }
}

__global__ void mean_kernel(const float* __restrict__ h0, float* __restrict__ mh)
{
    int idx = blockIdx.x * blockDim.x + threadIdx.x;   // 512*64
    if (idx < 512 * 64) {
        int g = idx >> 6, h = idx & 63;
        float s = 0.f;
        #pragma unroll
        for (int q = 0; q < 5; q++) s += h0[(size_t)(g * 5 + q) * 64 + h];
        mh[idx] = s * 0.2f;
    }
}

__global__ __launch_bounds__(64) void head_kernel(const float* __restrict__ x,
                                                  const float* __restrict__ mh,
                                                  const float* __restrict__ Wfc1,
                                                  const float* __restrict__ bfc1,
                                                  const float* __restrict__ Wfc2,
                                                  const float* __restrict__ bfc2,
                                                  float* __restrict__ out)
{
    __shared__ float sw[64];
    __shared__ float sh[64];
    int b = blockIdx.x, h = threadIdx.x;

    float a0 = 0.f, a1 = 0.f, a2 = 0.f, a3 = 0.f;
    const float* xr = x + (size_t)b * 512;
    for (int g = 0; g < 512; g += 4) {
        a0 = fmaf(xr[g + 0], mh[(g + 0) * 64 + h], a0);
        a1 = fmaf(xr[g + 1], mh[(g + 1) * 64 + h], a1);
        a2 = fmaf(xr[g + 2], mh[(g + 2) * 64 + h], a2);
        a3 = fmaf(xr[g + 3], mh[(g + 3) * 64 + h], a3);
    }
    sw[h] = (a0 + a1) + (a2 + a3);
    __syncthreads();

    float acc = bfc1[h];
    #pragma unroll 8
    for (int k = 0; k < 64; k++) acc = fmaf(Wfc1[h * 64 + k], sw[k], acc);
    sh[h] = fmaxf(acc, 0.f);
    __syncthreads();

    if (h < 8) {
        float o = bfc2[h];
        #pragma unroll 8
        for (int f = 0; f < 64; f++) o = fmaf(Wfc2[h * 64 + f], sh[f], o);
        out[(size_t)b * 8 + h] = o;
    }
}

extern "C" void kernel_launch(void* const* d_in, const int* in_sizes, int n_in,
                              void* d_out, int out_size, void* d_ws, size_t ws_size,
                              hipStream_t stream)
{
    (void)in_sizes; (void)n_in; (void)out_size; (void)ws_size;
    const float* x     = (const float*)d_in[0];
    const float* x0    = (const float*)d_in[1];
    const float* W_emb = (const float*)d_in[2];
    const float* b_emb = (const float*)d_in[3];
    const float* W0    = (const float*)d_in[4];
    const float* b0    = (const float*)d_in[5];
    const float* W1    = (const float*)d_in[6];
    const float* b1    = (const float*)d_in[7];
    const float* Wfc1  = (const float*)d_in[8];
    const float* bfc1  = (const float*)d_in[9];
    const float* Wfc2  = (const float*)d_in[10];
    const float* bfc2  = (const float*)d_in[11];

    unsigned short* wt1 = (unsigned short*)d_ws;       // 64*192
    unsigned short* wt0 = wt1 + 64 * 192;              // 64*64
    float* b1p = (float*)(wt0 + 64 * 64);
    float* b0p = b1p + 64;
    float* h0  = b0p + 64;                             // 2560*64
    float* mh  = h0 + 2560 * 64;                       // 512*64
    float* out = (float*)d_out;

    prep_kernel<<<65, 256, 0, stream>>>(W_emb, b_emb, W0, b0, W1, b1, wt1, wt0, b1p, b0p);
    tree_kernel<<<1280, 512, 0, stream>>>(x0, wt1, wt0, b1p, b0p, h0);
    mean_kernel<<<128, 256, 0, stream>>>(h0, mh);
    head_kernel<<<512, 64, 0, stream>>>(x, mh, Wfc1, bfc1, Wfc2, bfc2, out);
}

// Round 3
// 110.951 us; speedup vs baseline: 7.1792x; 1.1618x over previous
//
#include <hip/hip_runtime.h>
#include <hip/hip_bf16.h>

// ---------------------------------------------------------------------------
// Tree-MLP, MFMA bf16, round 3: 1 tree/block (48 KB LDS -> 2 blocks/CU),
// x0 register-prefetch across raw s_barrier (lgkmcnt-only drain).
// ---------------------------------------------------------------------------

typedef __attribute__((ext_vector_type(8))) short s8v;   // 8 bf16 = 4 VGPR
typedef __attribute__((ext_vector_type(4))) float f4v;   // MFMA C/D

__device__ __forceinline__ unsigned short f2bf(float f) {
    return __builtin_bit_cast(unsigned short, __float2bfloat16(f));
}
__device__ __forceinline__ f4v mfma16(s8v a, s8v b, f4v c) {
    return __builtin_amdgcn_mfma_f32_16x16x32_bf16(a, b, c, 0, 0, 0);
}

// LDS swizzle: 8-granular XOR of h-index with row bits {0,2,3}
#define SWZ(r) ((((r) & 1) | (((r) >> 1) & 6)) << 3)

// LDS-only barrier: drain lgkm (ds ops) but NOT vmcnt -> global prefetch
// survives the barrier. Post-barrier empty asm blocks LDS-read hoisting.
__device__ __forceinline__ void BAR() {
    asm volatile("s_waitcnt lgkmcnt(0)" ::: "memory");
    __builtin_amdgcn_s_barrier();
    asm volatile("" ::: "memory");
}

struct XL { float4 A, B, T; };   // raw f32 x0 fragment (k = lq*8..+7, tail 31..34)

__global__ void prep_kernel(const float* __restrict__ W_emb, const float* __restrict__ b_emb,
                            const float* __restrict__ W0, const float* __restrict__ b0,
                            const float* __restrict__ W1, const float* __restrict__ b1,
                            unsigned short* __restrict__ wt1, unsigned short* __restrict__ wt0,
                            float* __restrict__ b1p, float* __restrict__ b0p)
{
    int idx = blockIdx.x * 256 + threadIdx.x;
    if (idx < 64 * 192) {
        int h = idx / 192, k = idx % 192;
        float v;
        if (k < 32) { v = 0.f; for (int e = 0; e < 64; e++) v = fmaf(W1[h*195+e], W_emb[e*32+k], v); }
        else if (k < 35)  v = W1[h*195 + 64 + (k - 32)];
        else if (k < 64)  v = 0.f;
        else              v = W1[h*195 + 67 + (k - 64)];   // hL(64) then hR(64)
        wt1[h*192 + k] = f2bf(v);
    } else if (idx < 64*192 + 64*64) {
        int j = idx - 64*192; int h = j >> 6, k = j & 63;
        float v;
        if (k < 32)      { v = 0.f; for (int e = 0; e < 64; e++) v = fmaf(W0[h*67+e], W_emb[e*32+k], v); }
        else if (k < 35)   v = W0[h*67 + 64 + (k - 32)];
        else               v = 0.f;
        wt0[h*64 + k] = f2bf(v);
    } else if (idx < 64*192 + 64*64 + 64) {
        int h = idx - (64*192 + 64*64);
        float v = b1[h];
        for (int e = 0; e < 64; e++) v = fmaf(W1[h*195+e], b_emb[e], v);
        b1p[h] = v;
    } else if (idx < 64*192 + 64*64 + 128) {
        int h = idx - (64*192 + 64*64 + 64);
        float v = b0[h];
        for (int e = 0; e < 64; e++) v = fmaf(W0[h*67+e], b_emb[e], v);
        b0p[h] = v;
    }
}

__global__ __launch_bounds__(512, 4) void tree_kernel(
    const float* __restrict__ x0,
    const unsigned short* __restrict__ wt1,
    const unsigned short* __restrict__ wt0,
    const float* __restrict__ b1p,
    const float* __restrict__ b0p,
    float* __restrict__ h0out)
{
    __shared__ __align__(16) unsigned short buf0[256 * 64];  // 32 KB
    __shared__ __align__(16) unsigned short buf1[128 * 64];  // 16 KB

    const int l  = threadIdx.x & 63;
    const int w  = threadIdx.x >> 6;   // 0..7
    const int c2 = w & 1;              // col half (32 cols)
    const int wr = w >> 1;             // row split 0..3
    const int lq = l >> 4;
    const int lm = l & 15;
    const int p  = blockIdx.x;
    const float* xbase = x0 + (size_t)p * 511 * 35;

    auto xload = [&](int lo, int R0) -> XL {
        const float* xr = xbase + (size_t)(lo + R0 + lm) * 35;
        XL v;
        v.A = *(const float4*)(xr + lq * 8);
        v.B = *(const float4*)(xr + lq * 8 + 4);
        if (lq == 0) v.T = *(const float4*)(xr + 31);   // k31,32,33,34
        else         v.T = float4{0.f, 0.f, 0.f, 0.f};
        return v;
    };
    auto mk0 = [&](const XL& v) -> s8v {
        s8v r;
        r[0]=(short)f2bf(v.A.x); r[1]=(short)f2bf(v.A.y); r[2]=(short)f2bf(v.A.z); r[3]=(short)f2bf(v.A.w);
        r[4]=(short)f2bf(v.B.x); r[5]=(short)f2bf(v.B.y); r[6]=(short)f2bf(v.B.z); r[7]=(short)f2bf(v.B.w);
        return r;
    };
    auto mk1 = [&](const XL& v) -> s8v {   // k32..34 (lanes lq!=0 hold zeros)
        s8v r = {0,0,0,0,0,0,0,0};
        r[0]=(short)f2bf(v.T.y); r[1]=(short)f2bf(v.T.z); r[2]=(short)f2bf(v.T.w);
        return r;
    };
    auto store16 = [&](unsigned short* bufW, int R0, const f4v& acc0, const f4v& acc1) {
        #pragma unroll
        for (int r = 0; r < 4; r++) {
            int ro = R0 + lq * 4 + r;
            int sw = SWZ(ro);
            bufW[ro*64 + ((c2*32      + lm) ^ sw)] = f2bf(fmaxf(acc0[r], 0.f));
            bufW[ro*64 + ((c2*32 + 16 + lm) ^ sw)] = f2bf(fmaxf(acc1[r], 0.f));
        }
    };

    // ---- leaf (nodes 255..510, 256 rows, K=35, W0) ----
    {
        XL xl[4];
        #pragma unroll
        for (int t = 0; t < 4; t++) xl[t] = xload(255, (wr + 4*t) * 16);

        s8v wL[2][2]; f4v bi0[2];
        #pragma unroll
        for (int cc = 0; cc < 2; cc++) {
            int col = c2*32 + cc*16 + lm;
            wL[cc][0] = *(const s8v*)(wt0 + col*64 +      lq*8);
            wL[cc][1] = *(const s8v*)(wt0 + col*64 + 32 + lq*8);
            float bv = b0p[col];
            bi0[cc] = (f4v){bv, bv, bv, bv};
        }
        #pragma unroll
        for (int t = 0; t < 4; t++) {
            int R0 = (wr + 4*t) * 16;
            s8v a0 = mk0(xl[t]), a1 = mk1(xl[t]);
            f4v acc0 = bi0[0], acc1 = bi0[1];
            acc0 = mfma16(a0, wL[0][0], acc0);
            acc1 = mfma16(a0, wL[1][0], acc1);
            acc0 = mfma16(a1, wL[0][1], acc0);
            acc1 = mfma16(a1, wL[1][1], acc1);
            store16(buf0, R0, acc0, acc1);
        }
    }

    // internal weights (L2-hot; issued before barrier, used after)
    s8v wX[2][2], wH[2][4]; f4v bi1[2];
    #pragma unroll
    for (int cc = 0; cc < 2; cc++) {
        int col = c2*32 + cc*16 + lm;
        #pragma unroll
        for (int ks = 0; ks < 2; ks++) wX[cc][ks] = *(const s8v*)(wt1 + col*192 + ks*32 + lq*8);
        #pragma unroll
        for (int ks = 0; ks < 4; ks++) wH[cc][ks] = *(const s8v*)(wt1 + col*192 + 64 + ks*32 + lq*8);
        float bv = b1p[col];
        bi1[cc] = (f4v){bv, bv, bv, bv};
    }

    auto child_frag = [&](const unsigned short* bufR, int g, int ks) -> s8v {
        int k0 = ks*32 + lq*8;                 // 0..127 over [hL|hR]
        int rr = 2*g + (k0 >> 6);
        int off = (k0 & 63) ^ SWZ(rr);
        return *(const s8v*)(bufR + rr*64 + off);
    };
    auto ctile = [&](const unsigned short* bufR, unsigned short* bufW, const XL& xv, int R0) {
        s8v a0 = mk0(xv), a1 = mk1(xv);
        f4v acc0 = bi1[0], acc1 = bi1[1];
        acc0 = mfma16(a0, wX[0][0], acc0);
        acc1 = mfma16(a0, wX[1][0], acc1);
        acc0 = mfma16(a1, wX[0][1], acc0);
        acc1 = mfma16(a1, wX[1][1], acc1);
        int g = R0 + lm;
        #pragma unroll
        for (int ks = 0; ks < 4; ks++) {
            s8v a = child_frag(bufR, g, ks);
            acc0 = mfma16(a, wH[0][ks], acc0);
            acc1 = mfma16(a, wH[1][ks], acc1);
        }
        store16(bufW, R0, acc0, acc1);
    };

    // ---- l=7 (128 rows): prefetch issued pre-barrier ----
    XL x7a = xload(127, wr*16);
    XL x7b = xload(127, (wr + 4)*16);
    BAR();
    ctile(buf0, buf1, x7a, wr*16);
    ctile(buf0, buf1, x7b, (wr + 4)*16);

    // ---- l=6 (64 rows) ----
    XL x6 = xload(63, wr*16);
    BAR();
    ctile(buf1, buf0, x6, wr*16);

    // ---- l=5 (32 rows) ----
    XL x5; if (wr < 2) x5 = xload(31, wr*16);
    BAR();
    if (wr < 2) ctile(buf0, buf1, x5, wr*16);

    // ---- l=4 (16 rows) ----
    XL x4; if (wr == 0) x4 = xload(15, 0);
    BAR();
    if (wr == 0) ctile(buf1, buf0, x4, 0);

    // ---- l=3 (8 rows, padded tile) ----
    XL x3; if (wr == 0) x3 = xload(7, 0);
    BAR();
    if (wr == 0) ctile(buf0, buf1, x3, 0);

    // ---- l=2 (4 rows) ----
    XL x2; if (wr == 0) x2 = xload(3, 0);
    BAR();
    if (wr == 0) ctile(buf1, buf0, x2, 0);

    // ---- l=1 (2 rows) ----
    XL x1; if (wr == 0) x1 = xload(1, 0);
    BAR();
    if (wr == 0) ctile(buf0, buf1, x1, 0);

    // ---- l=0 (1 row) -> global ----
    XL xz; if (wr == 0) xz = xload(0, 0);
    BAR();
    if (wr == 0) {
        s8v a0 = mk0(xz), a1 = mk1(xz);
        f4v acc0 = bi1[0], acc1 = bi1[1];
        acc0 = mfma16(a0, wX[0][0], acc0);
        acc1 = mfma16(a0, wX[1][0], acc1);
        acc0 = mfma16(a1, wX[0][1], acc0);
        acc1 = mfma16(a1, wX[1][1], acc1);
        #pragma unroll
        for (int ks = 0; ks < 4; ks++) {
            s8v a = child_frag(buf1, lm, ks);   // g = lm (only g==0 kept)
            acc0 = mfma16(a, wH[0][ks], acc0);
            acc1 = mfma16(a, wH[1][ks], acc1);
        }
        if (lq == 0) {   // row 0 = node 0
            h0out[(size_t)p*64 + c2*32      + lm] = fmaxf(acc0[0], 0.f);
            h0out[(size_t)p*64 + c2*32 + 16 + lm] = fmaxf(acc1[0], 0.f);
        }
    }
}

__global__ void mean_kernel(const float* __restrict__ h0, float* __restrict__ mh)
{
    int idx = blockIdx.x * blockDim.x + threadIdx.x;   // 512*64
    if (idx < 512 * 64) {
        int g = idx >> 6, h = idx & 63;
        float s = 0.f;
        #pragma unroll
        for (int q = 0; q < 5; q++) s += h0[(size_t)(g * 5 + q) * 64 + h];
        mh[idx] = s * 0.2f;
    }
}

__global__ __launch_bounds__(64) void head_kernel(const float* __restrict__ x,
                                                  const float* __restrict__ mh,
                                                  const float* __restrict__ Wfc1,
                                                  const float* __restrict__ bfc1,
                                                  const float* __restrict__ Wfc2,
                                                  const float* __restrict__ bfc2,
                                                  float* __restrict__ out)
{
    __shared__ float sw[64];
    __shared__ float sh[64];
    int b = blockIdx.x, h = threadIdx.x;

    float a0 = 0.f, a1 = 0.f, a2 = 0.f, a3 = 0.f;
    const float* xr = x + (size_t)b * 512;
    for (int g = 0; g < 512; g += 4) {
        a0 = fmaf(xr[g + 0], mh[(g + 0) * 64 + h], a0);
        a1 = fmaf(xr[g + 1], mh[(g + 1) * 64 + h], a1);
        a2 = fmaf(xr[g + 2], mh[(g + 2) * 64 + h], a2);
        a3 = fmaf(xr[g + 3], mh[(g + 3) * 64 + h], a3);
    }
    sw[h] = (a0 + a1) + (a2 + a3);
    __syncthreads();

    float acc = bfc1[h];
    #pragma unroll 8
    for (int k = 0; k < 64; k++) acc = fmaf(Wfc1[h * 64 + k], sw[k], acc);
    sh[h] = fmaxf(acc, 0.f);
    __syncthreads();

    if (h < 8) {
        float o = bfc2[h];
        #pragma unroll 8
        for (int f = 0; f < 64; f++) o = fmaf(Wfc2[h * 64 + f], sh[f], o);
        out[(size_t)b * 8 + h] = o;
    }
}

extern "C" void kernel_launch(void* const* d_in, const int* in_sizes, int n_in,
                              void* d_out, int out_size, void* d_ws, size_t ws_size,
                              hipStream_t stream)
{
    (void)in_sizes; (void)n_in; (void)out_size; (void)ws_size;
    const float* x     = (const float*)d_in[0];
    const float* x0    = (const float*)d_in[1];
    const float* W_emb = (const float*)d_in[2];
    const float* b_emb = (const float*)d_in[3];
    const float* W0    = (const float*)d_in[4];
    const float* b0    = (const float*)d_in[5];
    const float* W1    = (const float*)d_in[6];
    const float* b1    = (const float*)d_in[7];
    const float* Wfc1  = (const float*)d_in[8];
    const float* bfc1  = (const float*)d_in[9];
    const float* Wfc2  = (const float*)d_in[10];
    const float* bfc2  = (const float*)d_in[11];

    unsigned short* wt1 = (unsigned short*)d_ws;       // 64*192
    unsigned short* wt0 = wt1 + 64 * 192;              // 64*64
    float* b1p = (float*)(wt0 + 64 * 64);
    float* b0p = b1p + 64;
    float* h0  = b0p + 64;                             // 2560*64
    float* mh  = h0 + 2560 * 64;                       // 512*64
    float* out = (float*)d_out;

    prep_kernel<<<65, 256, 0, stream>>>(W_emb, b_emb, W0, b0, W1, b1, wt1, wt0, b1p, b0p);
    tree_kernel<<<2560, 512, 0, stream>>>(x0, wt1, wt0, b1p, b0p, h0);
    mean_kernel<<<128, 256, 0, stream>>>(h0, mh);
    head_kernel<<<512, 64, 0, stream>>>(x, mh, Wfc1, bfc1, Wfc2, bfc2, out);
}